// Round 11
// baseline (707.603 us; speedup 1.0000x reference)
//
#include <hip/hip_runtime.h>
#include <hip/hip_bf16.h>
#include <hip/hip_fp16.h>

#define N_NODES 100000
#define N_EDGES 800000
#define N_GRAPHS 512
#define D 128
#define EPSV 1e-5f

// radix-bucket CSR build params (256-node buckets)
#define NBLK 256
#define EPB  3125
#define NBUK 391          // ceil(100000/256)
#define MAXB 3072

// MFMA GEMM LDS layout (dwords): Ah 64 rows x 68dw, Wt2 128 cols x 68dw
#define LSTR 68
#define WOFF 4352

// sliced aggregation: 8 passes x 16 features; slice = 3.2 MB (fits 4 MB L2/XCD)
#define NPASS 8
#define WPP   12500       // waves per pass (12500 * 8 nodes = 100000)

typedef _Float16 half8 __attribute__((ext_vector_type(8)));
typedef float floatx16 __attribute__((ext_vector_type(16)));

__device__ __forceinline__ float relu_f(float x){ return fmaxf(x, 0.0f); }

// ---------------- W prepack (fp16 W^T, 3 layers) + workspace zeroing ----------
__global__ __launch_bounds__(256) void k_wprep(const float* __restrict__ Ws,
                                               unsigned int* __restrict__ wpack,
                                               unsigned int* __restrict__ zbase,
                                               int zn)
{
    int idx = blockIdx.x * 256 + threadIdx.x;
    if (idx < 3 * 128 * 64){
        int l  = idx >> 13;
        int r  = idx & 8191;
        int c  = r >> 6;
        int k2 = r & 63;
        const float* W = Ws + l * D * D;
        __half2 h = __floats2half2_rn(W[(size_t)(2 * k2) * D + c],
                                      W[(size_t)(2 * k2 + 1) * D + c]);
        wpack[idx] = *(unsigned int*)&h;
    }
    int stride = gridDim.x * 256;
    for (int i = idx; i < zn; i += stride) zbase[i] = 0u;
}

// ---------------- P1: per-block bucket histogram (LDS only) ----------------
__global__ __launch_bounds__(256) void k_p1(const int* __restrict__ dst,
                                            int* __restrict__ blockHist)
{
    __shared__ int h[NBUK];
    int j = blockIdx.x, t = threadIdx.x;
    for (int u = t; u < NBUK; u += 256) h[u] = 0;
    __syncthreads();
    int e0 = j * EPB;
    for (int e = e0 + t; e < e0 + EPB; e += 256)
        atomicAdd(&h[dst[e] >> 8], 1);
    __syncthreads();
    for (int u = t; u < NBUK; u += 256) blockHist[j * NBUK + u] = h[u];
}

// ---------------- P2a: per-bucket column scan (NBUK blocks, parallel) ----------
__global__ __launch_bounds__(256) void k_p2a(const int* __restrict__ blockHist,
                                             int* __restrict__ colScan,
                                             int* __restrict__ bucketTotal)
{
    __shared__ int sd[256];
    int b = blockIdx.x, t = threadIdx.x;
    int v = blockHist[t * NBUK + b];
    sd[t] = v;
    __syncthreads();
    for (int off = 1; off < 256; off <<= 1){
        int u = (t >= off) ? sd[t - off] : 0;
        __syncthreads();
        sd[t] += u;
        __syncthreads();
    }
    colScan[t * NBUK + b] = sd[t] - v;
    if (t == 255) bucketTotal[b] = sd[255];
}

// ---------------- P2b: bucket-base scan (1 block x 512 thr) ----------------
__global__ __launch_bounds__(512) void k_p2b(const int* __restrict__ bucketTotal,
                                             int* __restrict__ bucketBase,
                                             int* __restrict__ row_ptr)
{
    __shared__ int sd[512];
    int b = threadIdx.x;
    int v = (b < NBUK) ? bucketTotal[b] : 0;
    sd[b] = v;
    __syncthreads();
    for (int off = 1; off < 512; off <<= 1){
        int u = (b >= off) ? sd[b - off] : 0;
        __syncthreads();
        sd[b] += u;
        __syncthreads();
    }
    if (b < NBUK) bucketBase[b] = sd[b] - v;
    if (b == 0){
        bucketBase[NBUK] = N_EDGES;
        row_ptr[N_NODES] = N_EDGES;
    }
}

// ---------------- P3: scatter edges into bucket-sorted ebuf (LDS cursors) ------
__global__ __launch_bounds__(256) void k_p3(const int* __restrict__ src,
                                            const int* __restrict__ dst,
                                            const int* __restrict__ colScan,
                                            const int* __restrict__ bucketBase,
                                            int2* __restrict__ ebuf)
{
    __shared__ int cur[NBUK];
    int j = blockIdx.x, t = threadIdx.x;
    for (int u = t; u < NBUK; u += 256)
        cur[u] = bucketBase[u] + colScan[j * NBUK + u];
    __syncthreads();
    int e0 = j * EPB;
    for (int e = e0 + t; e < e0 + EPB; e += 256){
        int s = src[e], d = dst[e];
        int pos = atomicAdd(&cur[d >> 8], 1);
        int2 v; v.x = s; v.y = d;
        ebuf[pos] = v;
    }
}

// ---------------- P4: per-bucket counting sort -> row_ptr, CSR, dinv, selfw ----
__global__ __launch_bounds__(256) void k_p4(const int2* __restrict__ ebuf,
                                            const int* __restrict__ bucketBase,
                                            int* __restrict__ row_ptr,
                                            int* __restrict__ csr_src,
                                            int* __restrict__ csr_dst,
                                            float* __restrict__ dinv,
                                            float* __restrict__ selfw)
{
    __shared__ int2 stash[MAXB];
    __shared__ int bins[256];
    __shared__ int sd[256];
    int b = blockIdx.x, t = threadIdx.x;
    int base = bucketBase[b];
    int cntb = bucketBase[b + 1] - base;
    bool st = (cntb <= MAXB);
    bins[t] = 0;
    __syncthreads();
    for (int i = t; i < cntb; i += 256){
        int2 ed = ebuf[base + i];
        if (st) stash[i] = ed;
        atomicAdd(&bins[ed.y & 255], 1);
    }
    __syncthreads();
    int a0 = bins[t];
    sd[t] = a0;
    __syncthreads();
    for (int off = 1; off < 256; off <<= 1){
        int v = (t >= off) ? sd[t - off] : 0;
        __syncthreads();
        sd[t] += v;
        __syncthreads();
    }
    int pex = sd[t] - a0;
    int node = b * 256 + t;
    if (node < N_NODES){
        row_ptr[node] = base + pex;
        float d = (float)(a0 + 1);
        dinv[node]  = rsqrtf(d);
        selfw[node] = 1.0f / d;
    }
    __syncthreads();
    bins[t] = pex;
    __syncthreads();
    for (int i = t; i < cntb; i += 256){
        int2 ed = st ? stash[i] : ebuf[base + i];
        int pos = atomicAdd(&bins[ed.y & 255], 1);
        csr_src[base + pos] = ed.x;
        csr_dst[base + pos] = ed.y;
    }
}

// ---------------- edge weights + per-graph counts (fused) ----------------
__global__ __launch_bounds__(256) void k_w(const int* __restrict__ csr_src,
                                           const int* __restrict__ csr_dst,
                                           const float* __restrict__ dinv,
                                           float* __restrict__ csr_w,
                                           const int* __restrict__ batch,
                                           float* __restrict__ cnt)
{
    int p = blockIdx.x * 256 + threadIdx.x;
    if (p < N_EDGES)
        csr_w[p] = dinv[csr_src[p]] * dinv[csr_dst[p]];
    if (p < N_GRAPHS){
        int g = p;
        int lo = 0, hi = N_NODES;
        while (lo < hi){ int m = (lo + hi) >> 1; if (batch[m] < g) lo = m + 1; else hi = m; }
        int lb = lo;
        lo = 0; hi = N_NODES;
        while (lo < hi){ int m = (lo + hi) >> 1; if (batch[m] < g + 1) lo = m + 1; else hi = m; }
        cnt[g] = (float)(lo - lb);
    }
}

// ---------------- MFMA GEMM: out = fp16(BN(A)) @ fp16(W), fp32 accum ----------
// A is fp32 (x or hbuf). W prepacked fp16 (k_wprep).
__global__ __launch_bounds__(256) void k_gemm(const float* __restrict__ A,
                                              const unsigned int* __restrict__ wp,
                                              const float* __restrict__ scale,
                                              const float* __restrict__ shift,
                                              __half* __restrict__ outh,
                                              int useBn)
{
    __shared__ unsigned int lds32[WOFF + 128 * LSTR];   // 52224 B
    int tid = threadIdx.x;
    int rowBase = blockIdx.x * 64;

    // ---- stage A (64 x 128) fp16, BN+ReLU fused ----
    #pragma unroll
    for (int rep = 0; rep < 8; rep++){
        int f  = rep * 256 + tid;
        int m  = f >> 5;
        int c4 = f & 31;
        int row = rowBase + m;
        if (row >= N_NODES) row = N_NODES - 1;
        float4 v = *(const float4*)(A + (size_t)row * D + c4 * 4);
        if (useBn){
            float4 sc = *(const float4*)(scale + c4 * 4);
            float4 sh = *(const float4*)(shift + c4 * 4);
            v.x = relu_f(fmaf(v.x, sc.x, sh.x));
            v.y = relu_f(fmaf(v.y, sc.y, sh.y));
            v.z = relu_f(fmaf(v.z, sc.z, sh.z));
            v.w = relu_f(fmaf(v.w, sc.w, sh.w));
        }
        __half2 h0 = __floats2half2_rn(v.x, v.y);
        __half2 h1 = __floats2half2_rn(v.z, v.w);
        uint2 u; u.x = *(unsigned int*)&h0; u.y = *(unsigned int*)&h1;
        *(uint2*)&lds32[m * LSTR + 2 * c4] = u;
    }
    // ---- stage prepacked W^T via uint4 copy ----
    {
        const uint4* gw = (const uint4*)wp;
        #pragma unroll
        for (int rep = 0; rep < 8; rep++){
            int f = rep * 256 + tid;
            int c = f >> 4;
            int q = f & 15;
            uint4 v = gw[f];
            *(uint4*)&lds32[WOFF + c * LSTR + 4 * q] = v;
        }
    }
    __syncthreads();

    int lane = tid & 63, wv = tid >> 6;
    int quad = lane >> 5;
    int ml   = (lane & 31) + (wv & 1) * 32;
    int cA   = (wv >> 1) * 64;
    int c0   = cA + (lane & 31);
    int c1   = c0 + 32;
    const unsigned int* aRow  = lds32 + ml * LSTR;
    const unsigned int* bRow0 = lds32 + WOFF + c0 * LSTR;
    const unsigned int* bRow1 = lds32 + WOFF + c1 * LSTR;
    floatx16 acc0 = {};
    floatx16 acc1 = {};
    #pragma unroll
    for (int ch = 0; ch < 8; ch++){
        int o = ch * 8 + quad * 4;
        half8 af = *(const half8*)(aRow  + o);
        half8 b0 = *(const half8*)(bRow0 + o);
        half8 b1 = *(const half8*)(bRow1 + o);
        acc0 = __builtin_amdgcn_mfma_f32_32x32x16_f16(af, b0, acc0, 0, 0, 0);
        acc1 = __builtin_amdgcn_mfma_f32_32x32x16_f16(af, b1, acc1, 0, 0, 0);
    }
    int rBase = rowBase + (wv & 1) * 32 + 4 * quad;
    #pragma unroll
    for (int r = 0; r < 16; r++){
        int outRow = rBase + (r & 3) + 8 * (r >> 2);
        if (outRow < N_NODES){
            outh[(size_t)outRow * D + c0] = __float2half(acc0[r]);
            outh[(size_t)outRow * D + c1] = __float2half(acc1[r]);
        }
    }
}

// ---------------- SLICED edge aggregation: 8 passes x 16 features --------------
// Wave = 8 nodes x 8 lanes; lane's half2 = features [pass*16+2fl, +1].
// Pass encoded in blockIdx order -> per-pass 3.2MB table slice stays L2-resident.
// Per-feature edge order identical to R9 (bit-exact vs unsliced).
__global__ __launch_bounds__(256) void k_aggs(const __half* __restrict__ t,
                                              const int* __restrict__ row_ptr,
                                              const int* __restrict__ csr_src,
                                              const float* __restrict__ csr_w,
                                              const float* __restrict__ selfw,
                                              const float* __restrict__ bias,
                                              float* __restrict__ outb)
{
    int W = (blockIdx.x * 256 + threadIdx.x) >> 6;     // wave id, [0, 100000)
    int lane = threadIdx.x & 63;
    int pass = W / WPP;
    int i = (W - pass * WPP) * 8 + (lane >> 3);        // node id
    int fl = lane & 7;                                  // half2 index in slice
    const __half2* t2 = (const __half2*)t + (size_t)pass * 8 + fl;
    int p0 = row_ptr[i], p1 = row_ptr[i + 1];
    float sw = selfw[i];
    float2 a = __half22float2(t2[(size_t)i * 64]);
    float ax = a.x * sw, ay = a.y * sw;
    int p = p0;
    for (; p + 8 <= p1; p += 8){
        int s[8]; float wv8[8];
        #pragma unroll
        for (int j = 0; j < 8; j++){ s[j] = csr_src[p + j]; }
        #pragma unroll
        for (int j = 0; j < 8; j++){ wv8[j] = csr_w[p + j]; }
        __half2 v[8];
        #pragma unroll
        for (int j = 0; j < 8; j++) v[j] = t2[(size_t)s[j] * 64];
        #pragma unroll
        for (int j = 0; j < 8; j++){
            float2 f = __half22float2(v[j]);
            ax = fmaf(wv8[j], f.x, ax);
            ay = fmaf(wv8[j], f.y, ay);
        }
    }
    for (; p + 4 <= p1; p += 4){
        int   s0 = csr_src[p],   s1 = csr_src[p+1], s2 = csr_src[p+2], s3 = csr_src[p+3];
        float w0 = csr_w[p],     w1 = csr_w[p+1],   w2 = csr_w[p+2],   w3 = csr_w[p+3];
        float2 v0 = __half22float2(t2[(size_t)s0 * 64]);
        float2 v1 = __half22float2(t2[(size_t)s1 * 64]);
        float2 v2 = __half22float2(t2[(size_t)s2 * 64]);
        float2 v3 = __half22float2(t2[(size_t)s3 * 64]);
        ax = fmaf(w0, v0.x, ax); ay = fmaf(w0, v0.y, ay);
        ax = fmaf(w1, v1.x, ax); ay = fmaf(w1, v1.y, ay);
        ax = fmaf(w2, v2.x, ax); ay = fmaf(w2, v2.y, ay);
        ax = fmaf(w3, v3.x, ax); ay = fmaf(w3, v3.y, ay);
    }
    for (; p < p1; ++p){
        int s = csr_src[p];
        float w = csr_w[p];
        float2 v = __half22float2(t2[(size_t)s * 64]);
        ax = fmaf(w, v.x, ax);
        ay = fmaf(w, v.y, ay);
    }
    float2 b2 = ((const float2*)bias)[pass * 8 + fl];
    float2 o; o.x = ax + b2.x; o.y = ay + b2.y;
    *(float2*)(outb + (size_t)i * D + pass * 16 + 2 * fl) = o;
}

// ---------------- BN stats (fp32 h) + fused finalize ----------------
__global__ __launch_bounds__(256) void k_stats(const float* __restrict__ h,
                                               float* __restrict__ S,
                                               float* __restrict__ Q,
                                               const float* __restrict__ gamma,
                                               const float* __restrict__ beta,
                                               float* __restrict__ sc,
                                               float* __restrict__ sh,
                                               int* __restrict__ done)
{
    __shared__ float sS[8][128];
    __shared__ float sQ[8][128];
    __shared__ int isLast;
    int g  = threadIdx.x >> 5;
    int c4 = threadIdx.x & 31;
    int r0 = blockIdx.x * 200;
    const float4* h4 = (const float4*)h;
    float4 s = make_float4(0.f, 0.f, 0.f, 0.f);
    float4 q = make_float4(0.f, 0.f, 0.f, 0.f);
    for (int r = r0 + g; r < r0 + 200; r += 8){
        float4 v = h4[(size_t)r * 32 + c4];
        s.x += v.x; s.y += v.y; s.z += v.z; s.w += v.w;
        q.x = fmaf(v.x, v.x, q.x);
        q.y = fmaf(v.y, v.y, q.y);
        q.z = fmaf(v.z, v.z, q.z);
        q.w = fmaf(v.w, v.w, q.w);
    }
    *(float4*)&sS[g][c4 * 4] = s;
    *(float4*)&sQ[g][c4 * 4] = q;
    __syncthreads();
    int f = threadIdx.x;
    if (f < 128){
        float acc = 0.f;
        #pragma unroll
        for (int j = 0; j < 8; j++) acc += sS[j][f];
        atomicAdd(&S[f], acc);
    } else {
        int f2 = f - 128;
        float acc = 0.f;
        #pragma unroll
        for (int j = 0; j < 8; j++) acc += sQ[j][f2];
        atomicAdd(&Q[f2], acc);
    }
    __threadfence();
    __syncthreads();
    if (threadIdx.x == 0)
        isLast = (atomicAdd(done, 1) == (int)gridDim.x - 1);
    __syncthreads();
    if (isLast && f < 128){
        float Sv = atomicAdd(&S[f], 0.0f);
        float Qv = atomicAdd(&Q[f], 0.0f);
        float mean = Sv * (1.0f / N_NODES);
        float var  = fmaxf(Qv * (1.0f / N_NODES) - mean * mean, 0.0f);
        float inv  = rsqrtf(var + EPSV);
        float gm = gamma[f] * inv;
        sc[f] = gm;
        sh[f] = beta[f] - mean * gm;
    }
}

// ---------------- pooled sum per graph (fp32 h) ----------------
#define CHUNK 64
__global__ __launch_bounds__(256) void k_pool(const float* __restrict__ h,
                                              const int* __restrict__ batch,
                                              const float* __restrict__ sc,
                                              const float* __restrict__ sh,
                                              float* __restrict__ pool)
{
    int lane = threadIdx.x & 63;
    int wave = (blockIdx.x * blockDim.x + threadIdx.x) >> 6;
    int i0 = wave * CHUNK;
    if (i0 >= N_NODES) return;
    int i1 = min(N_NODES, i0 + CHUNK);
    const float2* h2 = (const float2*)h;
    float2 scv = ((const float2*)sc)[lane];
    float2 shv = ((const float2*)sh)[lane];
    int g = batch[i0];
    float ax = 0.f, ay = 0.f;
    for (int i = i0; i < i1; ++i){
        int gi = batch[i];
        if (gi != g){
            atomicAdd(&pool[g * 128 + 2 * lane],     ax);
            atomicAdd(&pool[g * 128 + 2 * lane + 1], ay);
            ax = 0.f; ay = 0.f; g = gi;
        }
        float2 v = h2[(size_t)i * 64 + lane];
        ax += relu_f(fmaf(v.x, scv.x, shv.x));
        ay += relu_f(fmaf(v.y, scv.y, shv.y));
    }
    atomicAdd(&pool[g * 128 + 2 * lane],     ax);
    atomicAdd(&pool[g * 128 + 2 * lane + 1], ay);
}

// ---------------- MLP head ----------------
__global__ __launch_bounds__(128) void k_head(const float* __restrict__ pool,
                                              const float* __restrict__ cnt,
                                              const float* __restrict__ W1,
                                              const float* __restrict__ b1,
                                              const float* __restrict__ W2,
                                              const float* __restrict__ b2,
                                              float* __restrict__ out)
{
    __shared__ float z[128];
    __shared__ float red[128];
    int g = blockIdx.x, f = threadIdx.x;
    float c = fmaxf(cnt[g], 1.0f);
    z[f] = pool[g * 128 + f] / c;
    __syncthreads();
    float a = b1[f];
    #pragma unroll 8
    for (int k = 0; k < 128; k++)
        a = fmaf(z[k], W1[k * 128 + f], a);
    a = relu_f(a);
    red[f] = a * W2[f];
    __syncthreads();
    for (int s2 = 64; s2 > 0; s2 >>= 1){
        if (f < s2) red[f] += red[f + s2];
        __syncthreads();
    }
    if (f == 0) out[g] = red[0] + b2[0];
}

extern "C" void kernel_launch(void* const* d_in, const int* in_sizes, int n_in,
                              void* d_out, int out_size, void* d_ws, size_t ws_size,
                              hipStream_t stream)
{
    const float* x      = (const float*)d_in[0];
    const int*   ei     = (const int*)d_in[1];
    const int*   batch  = (const int*)d_in[2];
    const float* Ws     = (const float*)d_in[3];
    const float* bs     = (const float*)d_in[4];
    const float* gammas = (const float*)d_in[5];
    const float* betas  = (const float*)d_in[6];
    const float* W1     = (const float*)d_in[7];
    const float* b1     = (const float*)d_in[8];
    const float* W2     = (const float*)d_in[9];
    const float* b2     = (const float*)d_in[10];
    float* out = (float*)d_out;

    const int* src = ei;
    const int* dst = ei + N_EDGES;

    char* w = (char*)d_ws;
    size_t off = 0;
    auto alloc = [&](size_t bytes) -> void* {
        void* p = w + off;
        off += (bytes + 255) & ~(size_t)255;
        return p;
    };
    int*   row_ptr     = (int*)  alloc((size_t)(N_NODES + 1) * 4);
    float* dinv        = (float*)alloc((size_t)N_NODES * 4);
    float* selfw       = (float*)alloc((size_t)N_NODES * 4);
    int*   csr_src     = (int*)  alloc((size_t)N_EDGES * 4);
    float* csr_w       = (float*)alloc((size_t)N_EDGES * 4);
    int*   blockHist   = (int*)  alloc((size_t)NBLK * NBUK * 4);
    int*   colScan     = (int*)  alloc((size_t)NBLK * NBUK * 4);
    int*   bucketBase  = (int*)  alloc((size_t)(NBUK + 1) * 4);
    int*   bucketTotal = (int*)  alloc((size_t)NBUK * 4);
    unsigned int* wpack = (unsigned int*)alloc((size_t)3 * 128 * 64 * 4);
    size_t zoff = off;                       // --- zero-span start ---
    float* stats       = (float*)alloc(3 * 256 * 4);   // per layer: S, Q
    int*   done        = (int*)  alloc(3 * 4);
    float* pool        = (float*)alloc((size_t)N_GRAPHS * 128 * 4);
    size_t zend = off;                       // --- zero-span end ---
    float* cnt         = (float*)alloc((size_t)N_GRAPHS * 4);
    float* ssh         = (float*)alloc(3 * 256 * 4);   // per layer: scale, shift
    __half* tbuf       = (__half*)alloc((size_t)N_NODES * 128 * 2);  // fp16 gather table
    float* hbuf        = (float*)alloc((size_t)N_NODES * 128 * 4);   // fp32 h
    if (off > ws_size) return;

    // alias scratch (consumed before tbuf/hbuf are first written; stream-ordered)
    int2* ebuf    = (int2*)tbuf;    // 6.4 MB < 25.6 MB
    int*  csr_dst = (int*)hbuf;     // 3.2 MB < 51.2 MB

    k_wprep<<<128, 256, 0, stream>>>(Ws, wpack,
                                     (unsigned int*)(w + zoff),
                                     (int)((zend - zoff) >> 2));
    k_p1 <<<NBLK, 256, 0, stream>>>(dst, blockHist);
    k_p2a<<<NBUK, 256, 0, stream>>>(blockHist, colScan, bucketTotal);
    k_p2b<<<1,    512, 0, stream>>>(bucketTotal, bucketBase, row_ptr);
    k_p3 <<<NBLK, 256, 0, stream>>>(src, dst, colScan, bucketBase, ebuf);
    k_p4 <<<NBUK, 256, 0, stream>>>(ebuf, bucketBase, row_ptr, csr_src, csr_dst, dinv, selfw);
    k_w  <<<(N_EDGES + 255) / 256, 256, 0, stream>>>(csr_src, csr_dst, dinv, csr_w, batch, cnt);

    const float* curIn = x;
    for (int l = 0; l < 3; l++){
        k_gemm<<<(N_NODES + 63) / 64, 256, 0, stream>>>(
            curIn, wpack + l * 8192,
            l ? ssh + (l - 1) * 256       : nullptr,
            l ? ssh + (l - 1) * 256 + 128 : nullptr,
            tbuf, l ? 1 : 0);
        k_aggs<<<(WPP * NPASS) / 4, 256, 0, stream>>>(
            tbuf, row_ptr, csr_src, csr_w, selfw,
            bs + l * 128, hbuf);
        k_stats<<<500, 256, 0, stream>>>(
            hbuf, stats + l * 256, stats + l * 256 + 128,
            gammas + l * 128, betas + l * 128,
            ssh + l * 256, ssh + l * 256 + 128, done + l);
        curIn = hbuf;
    }

    k_pool<<<391, 256, 0, stream>>>(hbuf, batch, ssh + 2 * 256, ssh + 2 * 256 + 128, pool);
    k_head<<<512, 128, 0, stream>>>(pool, cnt, W1, b1, W2, b2, out);
}

// Round 12
// 528.556 us; speedup vs baseline: 1.3387x; 1.3387x over previous
//
#include <hip/hip_runtime.h>
#include <hip/hip_bf16.h>
#include <hip/hip_fp16.h>

#define N_NODES 100000
#define N_EDGES 800000
#define N_GRAPHS 512
#define D 128
#define EPSV 1e-5f

// radix-bucket CSR build params (256-node buckets)
#define NBLK 256
#define EPB  3125
#define NBUK 391          // ceil(100000/256)
#define MAXB 3072

// MFMA GEMM: W^T in LDS, 128 cols x 68 dw (16B-aligned rows, 4-way bank alias)
#define LSTR 68

typedef _Float16 half8 __attribute__((ext_vector_type(8)));
typedef float floatx16 __attribute__((ext_vector_type(16)));

__device__ __forceinline__ float relu_f(float x){ return fmaxf(x, 0.0f); }

// ---------------- W prepack (fp16 W^T, 3 layers) + workspace zeroing ----------
__global__ __launch_bounds__(256) void k_wprep(const float* __restrict__ Ws,
                                               unsigned int* __restrict__ wpack,
                                               unsigned int* __restrict__ zbase,
                                               int zn)
{
    int idx = blockIdx.x * 256 + threadIdx.x;
    if (idx < 3 * 128 * 64){
        int l  = idx >> 13;
        int r  = idx & 8191;
        int c  = r >> 6;
        int k2 = r & 63;
        const float* W = Ws + l * D * D;
        __half2 h = __floats2half2_rn(W[(size_t)(2 * k2) * D + c],
                                      W[(size_t)(2 * k2 + 1) * D + c]);
        wpack[idx] = *(unsigned int*)&h;
    }
    int stride = gridDim.x * 256;
    for (int i = idx; i < zn; i += stride) zbase[i] = 0u;
}

// ---------------- P1: per-block bucket histogram (LDS only) ----------------
__global__ __launch_bounds__(256) void k_p1(const int* __restrict__ dst,
                                            int* __restrict__ blockHist)
{
    __shared__ int h[NBUK];
    int j = blockIdx.x, t = threadIdx.x;
    for (int u = t; u < NBUK; u += 256) h[u] = 0;
    __syncthreads();
    int e0 = j * EPB;
    for (int e = e0 + t; e < e0 + EPB; e += 256)
        atomicAdd(&h[dst[e] >> 8], 1);
    __syncthreads();
    for (int u = t; u < NBUK; u += 256) blockHist[j * NBUK + u] = h[u];
}

// ---------------- P2a: per-bucket column scan (NBUK blocks, parallel) ----------
__global__ __launch_bounds__(256) void k_p2a(const int* __restrict__ blockHist,
                                             int* __restrict__ colScan,
                                             int* __restrict__ bucketTotal)
{
    __shared__ int sd[256];
    int b = blockIdx.x, t = threadIdx.x;
    int v = blockHist[t * NBUK + b];
    sd[t] = v;
    __syncthreads();
    for (int off = 1; off < 256; off <<= 1){
        int u = (t >= off) ? sd[t - off] : 0;
        __syncthreads();
        sd[t] += u;
        __syncthreads();
    }
    colScan[t * NBUK + b] = sd[t] - v;
    if (t == 255) bucketTotal[b] = sd[255];
}

// ---------------- P2b: bucket-base scan (1 block x 512 thr) ----------------
__global__ __launch_bounds__(512) void k_p2b(const int* __restrict__ bucketTotal,
                                             int* __restrict__ bucketBase,
                                             int* __restrict__ row_ptr)
{
    __shared__ int sd[512];
    int b = threadIdx.x;
    int v = (b < NBUK) ? bucketTotal[b] : 0;
    sd[b] = v;
    __syncthreads();
    for (int off = 1; off < 512; off <<= 1){
        int u = (b >= off) ? sd[b - off] : 0;
        __syncthreads();
        sd[b] += u;
        __syncthreads();
    }
    if (b < NBUK) bucketBase[b] = sd[b] - v;
    if (b == 0){
        bucketBase[NBUK] = N_EDGES;
        row_ptr[N_NODES] = N_EDGES;
    }
}

// ---------------- P3: scatter edges into bucket-sorted ebuf (LDS cursors) ------
__global__ __launch_bounds__(256) void k_p3(const int* __restrict__ src,
                                            const int* __restrict__ dst,
                                            const int* __restrict__ colScan,
                                            const int* __restrict__ bucketBase,
                                            int2* __restrict__ ebuf)
{
    __shared__ int cur[NBUK];
    int j = blockIdx.x, t = threadIdx.x;
    for (int u = t; u < NBUK; u += 256)
        cur[u] = bucketBase[u] + colScan[j * NBUK + u];
    __syncthreads();
    int e0 = j * EPB;
    for (int e = e0 + t; e < e0 + EPB; e += 256){
        int s = src[e], d = dst[e];
        int pos = atomicAdd(&cur[d >> 8], 1);
        int2 v; v.x = s; v.y = d;
        ebuf[pos] = v;
    }
}

// ---------------- P4: per-bucket counting sort -> row_ptr, CSR, dinv, selfw ----
__global__ __launch_bounds__(256) void k_p4(const int2* __restrict__ ebuf,
                                            const int* __restrict__ bucketBase,
                                            int* __restrict__ row_ptr,
                                            int* __restrict__ csr_src,
                                            int* __restrict__ csr_dst,
                                            float* __restrict__ dinv,
                                            float* __restrict__ selfw)
{
    __shared__ int2 stash[MAXB];
    __shared__ int bins[256];
    __shared__ int sd[256];
    int b = blockIdx.x, t = threadIdx.x;
    int base = bucketBase[b];
    int cntb = bucketBase[b + 1] - base;
    bool st = (cntb <= MAXB);
    bins[t] = 0;
    __syncthreads();
    for (int i = t; i < cntb; i += 256){
        int2 ed = ebuf[base + i];
        if (st) stash[i] = ed;
        atomicAdd(&bins[ed.y & 255], 1);
    }
    __syncthreads();
    int a0 = bins[t];
    sd[t] = a0;
    __syncthreads();
    for (int off = 1; off < 256; off <<= 1){
        int v = (t >= off) ? sd[t - off] : 0;
        __syncthreads();
        sd[t] += v;
        __syncthreads();
    }
    int pex = sd[t] - a0;
    int node = b * 256 + t;
    if (node < N_NODES){
        row_ptr[node] = base + pex;
        float d = (float)(a0 + 1);
        dinv[node]  = rsqrtf(d);
        selfw[node] = 1.0f / d;
    }
    __syncthreads();
    bins[t] = pex;
    __syncthreads();
    for (int i = t; i < cntb; i += 256){
        int2 ed = st ? stash[i] : ebuf[base + i];
        int pos = atomicAdd(&bins[ed.y & 255], 1);
        csr_src[base + pos] = ed.x;
        csr_dst[base + pos] = ed.y;
    }
}

// ---------------- edge weights + per-graph counts (fused) ----------------
__global__ __launch_bounds__(256) void k_w(const int* __restrict__ csr_src,
                                           const int* __restrict__ csr_dst,
                                           const float* __restrict__ dinv,
                                           float* __restrict__ csr_w,
                                           const int* __restrict__ batch,
                                           float* __restrict__ cnt)
{
    int p = blockIdx.x * 256 + threadIdx.x;
    if (p < N_EDGES)
        csr_w[p] = dinv[csr_src[p]] * dinv[csr_dst[p]];
    if (p < N_GRAPHS){
        int g = p;
        int lo = 0, hi = N_NODES;
        while (lo < hi){ int m = (lo + hi) >> 1; if (batch[m] < g) lo = m + 1; else hi = m; }
        int lb = lo;
        lo = 0; hi = N_NODES;
        while (lo < hi){ int m = (lo + hi) >> 1; if (batch[m] < g + 1) lo = m + 1; else hi = m; }
        cnt[g] = (float)(lo - lb);
    }
}

// ---------------- MFMA GEMM v3: A direct-from-global, W in LDS ----------------
// Per lane: its own A row slice (k = ch*16 + quad*8, 8 floats = 2 dwordx4),
// BN+ReLU+fp16 cvt in-register. Removes A LDS round-trip; LDS 34.8 KB -> 4 blk/CU.
__global__ __launch_bounds__(256) void k_gemm(const float* __restrict__ A,
                                              const unsigned int* __restrict__ wp,
                                              const float* __restrict__ scale,
                                              const float* __restrict__ shift,
                                              __half* __restrict__ outh,
                                              int useBn)
{
    __shared__ unsigned int wlds[128 * LSTR];   // 34816 B
    int tid = threadIdx.x;
    int rowBase = blockIdx.x * 64;

    // stage prepacked W^T via uint4 copy (shared by all 4 waves)
    {
        const uint4* gw = (const uint4*)wp;
        #pragma unroll
        for (int rep = 0; rep < 8; rep++){
            int f = rep * 256 + tid;
            int c = f >> 4;
            int q = f & 15;
            uint4 v = gw[f];
            *(uint4*)&wlds[c * LSTR + 4 * q] = v;
        }
    }
    __syncthreads();

    int lane = tid & 63, wv = tid >> 6;
    int quad = lane >> 5;
    int ml   = (lane & 31) + (wv & 1) * 32;
    int row  = rowBase + ml;
    if (row >= N_NODES) row = N_NODES - 1;
    const float* aG = A + (size_t)row * D + quad * 8;
    int cA   = (wv >> 1) * 64;
    int c0   = cA + (lane & 31);
    int c1   = c0 + 32;
    const unsigned int* bRow0 = wlds + c0 * LSTR;
    const unsigned int* bRow1 = wlds + c1 * LSTR;
    floatx16 acc0 = {};
    floatx16 acc1 = {};
    #pragma unroll
    for (int ch = 0; ch < 8; ch++){
        float4 f0 = *(const float4*)(aG + ch * 16);
        float4 f1 = *(const float4*)(aG + ch * 16 + 4);
        if (useBn){
            int kb = ch * 16 + quad * 8;
            float4 s0 = *(const float4*)(scale + kb);
            float4 s1 = *(const float4*)(scale + kb + 4);
            float4 h0 = *(const float4*)(shift + kb);
            float4 h1 = *(const float4*)(shift + kb + 4);
            f0.x = relu_f(fmaf(f0.x, s0.x, h0.x));
            f0.y = relu_f(fmaf(f0.y, s0.y, h0.y));
            f0.z = relu_f(fmaf(f0.z, s0.z, h0.z));
            f0.w = relu_f(fmaf(f0.w, s0.w, h0.w));
            f1.x = relu_f(fmaf(f1.x, s1.x, h1.x));
            f1.y = relu_f(fmaf(f1.y, s1.y, h1.y));
            f1.z = relu_f(fmaf(f1.z, s1.z, h1.z));
            f1.w = relu_f(fmaf(f1.w, s1.w, h1.w));
        }
        half8 af;
        af[0] = (_Float16)f0.x; af[1] = (_Float16)f0.y;
        af[2] = (_Float16)f0.z; af[3] = (_Float16)f0.w;
        af[4] = (_Float16)f1.x; af[5] = (_Float16)f1.y;
        af[6] = (_Float16)f1.z; af[7] = (_Float16)f1.w;
        int o = ch * 8 + quad * 4;
        half8 b0 = *(const half8*)(bRow0 + o);
        half8 b1 = *(const half8*)(bRow1 + o);
        acc0 = __builtin_amdgcn_mfma_f32_32x32x16_f16(af, b0, acc0, 0, 0, 0);
        acc1 = __builtin_amdgcn_mfma_f32_32x32x16_f16(af, b1, acc1, 0, 0, 0);
    }
    int rBase = rowBase + (wv & 1) * 32 + 4 * quad;
    #pragma unroll
    for (int r = 0; r < 16; r++){
        int outRow = rBase + (r & 3) + 8 * (r >> 2);
        if (outRow < N_NODES){
            outh[(size_t)outRow * D + c0] = __float2half(acc0[r]);
            outh[(size_t)outRow * D + c1] = __float2half(acc1[r]);
        }
    }
}

// ---------------- edge aggregation + bias (fp16 gathers, fp32 accum/out) -------
__global__ __launch_bounds__(256) void k_agg(const __half* __restrict__ t,
                                             const int* __restrict__ row_ptr,
                                             const int* __restrict__ csr_src,
                                             const float* __restrict__ csr_w,
                                             const float* __restrict__ selfw,
                                             const float* __restrict__ bias,
                                             float* __restrict__ outb)
{
    int lane = threadIdx.x & 63;
    int i = (blockIdx.x * blockDim.x + threadIdx.x) >> 6;
    if (i >= N_NODES) return;
    const __half2* t2 = (const __half2*)t;
    int p0 = row_ptr[i], p1 = row_ptr[i + 1];
    float sw = selfw[i];
    float2 a = __half22float2(t2[(size_t)i * 64 + lane]);
    float ax = a.x * sw, ay = a.y * sw;
    int p = p0;
    for (; p + 8 <= p1; p += 8){
        int s[8]; float wv8[8];
        #pragma unroll
        for (int j = 0; j < 8; j++){ s[j] = csr_src[p + j]; }
        #pragma unroll
        for (int j = 0; j < 8; j++){ wv8[j] = csr_w[p + j]; }
        __half2 v[8];
        #pragma unroll
        for (int j = 0; j < 8; j++) v[j] = t2[(size_t)s[j] * 64 + lane];
        #pragma unroll
        for (int j = 0; j < 8; j++){
            float2 f = __half22float2(v[j]);
            ax = fmaf(wv8[j], f.x, ax);
            ay = fmaf(wv8[j], f.y, ay);
        }
    }
    for (; p + 4 <= p1; p += 4){
        int   s0 = csr_src[p],   s1 = csr_src[p+1], s2 = csr_src[p+2], s3 = csr_src[p+3];
        float w0 = csr_w[p],     w1 = csr_w[p+1],   w2 = csr_w[p+2],   w3 = csr_w[p+3];
        float2 v0 = __half22float2(t2[(size_t)s0 * 64 + lane]);
        float2 v1 = __half22float2(t2[(size_t)s1 * 64 + lane]);
        float2 v2 = __half22float2(t2[(size_t)s2 * 64 + lane]);
        float2 v3 = __half22float2(t2[(size_t)s3 * 64 + lane]);
        ax = fmaf(w0, v0.x, ax); ay = fmaf(w0, v0.y, ay);
        ax = fmaf(w1, v1.x, ax); ay = fmaf(w1, v1.y, ay);
        ax = fmaf(w2, v2.x, ax); ay = fmaf(w2, v2.y, ay);
        ax = fmaf(w3, v3.x, ax); ay = fmaf(w3, v3.y, ay);
    }
    for (; p < p1; ++p){
        int s = csr_src[p];
        float w = csr_w[p];
        float2 v = __half22float2(t2[(size_t)s * 64 + lane]);
        ax = fmaf(w, v.x, ax);
        ay = fmaf(w, v.y, ay);
    }
    float2 b2 = ((const float2*)bias)[lane];
    float2 o; o.x = ax + b2.x; o.y = ay + b2.y;
    ((float2*)outb)[(size_t)i * 64 + lane] = o;
}

// ---------------- BN stats (fp32 h) + fused finalize ----------------
__global__ __launch_bounds__(256) void k_stats(const float* __restrict__ h,
                                               float* __restrict__ S,
                                               float* __restrict__ Q,
                                               const float* __restrict__ gamma,
                                               const float* __restrict__ beta,
                                               float* __restrict__ sc,
                                               float* __restrict__ sh,
                                               int* __restrict__ done)
{
    __shared__ float sS[8][128];
    __shared__ float sQ[8][128];
    __shared__ int isLast;
    int g  = threadIdx.x >> 5;
    int c4 = threadIdx.x & 31;
    int r0 = blockIdx.x * 200;
    const float4* h4 = (const float4*)h;
    float4 s = make_float4(0.f, 0.f, 0.f, 0.f);
    float4 q = make_float4(0.f, 0.f, 0.f, 0.f);
    for (int r = r0 + g; r < r0 + 200; r += 8){
        float4 v = h4[(size_t)r * 32 + c4];
        s.x += v.x; s.y += v.y; s.z += v.z; s.w += v.w;
        q.x = fmaf(v.x, v.x, q.x);
        q.y = fmaf(v.y, v.y, q.y);
        q.z = fmaf(v.z, v.z, q.z);
        q.w = fmaf(v.w, v.w, q.w);
    }
    *(float4*)&sS[g][c4 * 4] = s;
    *(float4*)&sQ[g][c4 * 4] = q;
    __syncthreads();
    int f = threadIdx.x;
    if (f < 128){
        float acc = 0.f;
        #pragma unroll
        for (int j = 0; j < 8; j++) acc += sS[j][f];
        atomicAdd(&S[f], acc);
    } else {
        int f2 = f - 128;
        float acc = 0.f;
        #pragma unroll
        for (int j = 0; j < 8; j++) acc += sQ[j][f2];
        atomicAdd(&Q[f2], acc);
    }
    __threadfence();
    __syncthreads();
    if (threadIdx.x == 0)
        isLast = (atomicAdd(done, 1) == (int)gridDim.x - 1);
    __syncthreads();
    if (isLast && f < 128){
        float Sv = atomicAdd(&S[f], 0.0f);
        float Qv = atomicAdd(&Q[f], 0.0f);
        float mean = Sv * (1.0f / N_NODES);
        float var  = fmaxf(Qv * (1.0f / N_NODES) - mean * mean, 0.0f);
        float inv  = rsqrtf(var + EPSV);
        float gm = gamma[f] * inv;
        sc[f] = gm;
        sh[f] = beta[f] - mean * gm;
    }
}

// ---------------- pooled sum per graph (fp32 h) ----------------
#define CHUNK 64
__global__ __launch_bounds__(256) void k_pool(const float* __restrict__ h,
                                              const int* __restrict__ batch,
                                              const float* __restrict__ sc,
                                              const float* __restrict__ sh,
                                              float* __restrict__ pool)
{
    int lane = threadIdx.x & 63;
    int wave = (blockIdx.x * blockDim.x + threadIdx.x) >> 6;
    int i0 = wave * CHUNK;
    if (i0 >= N_NODES) return;
    int i1 = min(N_NODES, i0 + CHUNK);
    const float2* h2 = (const float2*)h;
    float2 scv = ((const float2*)sc)[lane];
    float2 shv = ((const float2*)sh)[lane];
    int g = batch[i0];
    float ax = 0.f, ay = 0.f;
    for (int i = i0; i < i1; ++i){
        int gi = batch[i];
        if (gi != g){
            atomicAdd(&pool[g * 128 + 2 * lane],     ax);
            atomicAdd(&pool[g * 128 + 2 * lane + 1], ay);
            ax = 0.f; ay = 0.f; g = gi;
        }
        float2 v = h2[(size_t)i * 64 + lane];
        ax += relu_f(fmaf(v.x, scv.x, shv.x));
        ay += relu_f(fmaf(v.y, scv.y, shv.y));
    }
    atomicAdd(&pool[g * 128 + 2 * lane],     ax);
    atomicAdd(&pool[g * 128 + 2 * lane + 1], ay);
}

// ---------------- MLP head ----------------
__global__ __launch_bounds__(128) void k_head(const float* __restrict__ pool,
                                              const float* __restrict__ cnt,
                                              const float* __restrict__ W1,
                                              const float* __restrict__ b1,
                                              const float* __restrict__ W2,
                                              const float* __restrict__ b2,
                                              float* __restrict__ out)
{
    __shared__ float z[128];
    __shared__ float red[128];
    int g = blockIdx.x, f = threadIdx.x;
    float c = fmaxf(cnt[g], 1.0f);
    z[f] = pool[g * 128 + f] / c;
    __syncthreads();
    float a = b1[f];
    #pragma unroll 8
    for (int k = 0; k < 128; k++)
        a = fmaf(z[k], W1[k * 128 + f], a);
    a = relu_f(a);
    red[f] = a * W2[f];
    __syncthreads();
    for (int s2 = 64; s2 > 0; s2 >>= 1){
        if (f < s2) red[f] += red[f + s2];
        __syncthreads();
    }
    if (f == 0) out[g] = red[0] + b2[0];
}

extern "C" void kernel_launch(void* const* d_in, const int* in_sizes, int n_in,
                              void* d_out, int out_size, void* d_ws, size_t ws_size,
                              hipStream_t stream)
{
    const float* x      = (const float*)d_in[0];
    const int*   ei     = (const int*)d_in[1];
    const int*   batch  = (const int*)d_in[2];
    const float* Ws     = (const float*)d_in[3];
    const float* bs     = (const float*)d_in[4];
    const float* gammas = (const float*)d_in[5];
    const float* betas  = (const float*)d_in[6];
    const float* W1     = (const float*)d_in[7];
    const float* b1     = (const float*)d_in[8];
    const float* W2     = (const float*)d_in[9];
    const float* b2     = (const float*)d_in[10];
    float* out = (float*)d_out;

    const int* src = ei;
    const int* dst = ei + N_EDGES;

    char* w = (char*)d_ws;
    size_t off = 0;
    auto alloc = [&](size_t bytes) -> void* {
        void* p = w + off;
        off += (bytes + 255) & ~(size_t)255;
        return p;
    };
    int*   row_ptr     = (int*)  alloc((size_t)(N_NODES + 1) * 4);
    float* dinv        = (float*)alloc((size_t)N_NODES * 4);
    float* selfw       = (float*)alloc((size_t)N_NODES * 4);
    int*   csr_src     = (int*)  alloc((size_t)N_EDGES * 4);
    float* csr_w       = (float*)alloc((size_t)N_EDGES * 4);
    int*   blockHist   = (int*)  alloc((size_t)NBLK * NBUK * 4);
    int*   colScan     = (int*)  alloc((size_t)NBLK * NBUK * 4);
    int*   bucketBase  = (int*)  alloc((size_t)(NBUK + 1) * 4);
    int*   bucketTotal = (int*)  alloc((size_t)NBUK * 4);
    unsigned int* wpack = (unsigned int*)alloc((size_t)3 * 128 * 64 * 4);
    size_t zoff = off;                       // --- zero-span start ---
    float* stats       = (float*)alloc(3 * 256 * 4);   // per layer: S, Q
    int*   done        = (int*)  alloc(3 * 4);
    float* pool        = (float*)alloc((size_t)N_GRAPHS * 128 * 4);
    size_t zend = off;                       // --- zero-span end ---
    float* cnt         = (float*)alloc((size_t)N_GRAPHS * 4);
    float* ssh         = (float*)alloc(3 * 256 * 4);   // per layer: scale, shift
    __half* tbuf       = (__half*)alloc((size_t)N_NODES * 128 * 2);  // fp16 gather table
    float* hbuf        = (float*)alloc((size_t)N_NODES * 128 * 4);   // fp32 h
    if (off > ws_size) return;

    // alias scratch (consumed before tbuf/hbuf are first written; stream-ordered)
    int2* ebuf    = (int2*)tbuf;    // 6.4 MB < 25.6 MB
    int*  csr_dst = (int*)hbuf;     // 3.2 MB < 51.2 MB

    k_wprep<<<128, 256, 0, stream>>>(Ws, wpack,
                                     (unsigned int*)(w + zoff),
                                     (int)((zend - zoff) >> 2));
    k_p1 <<<NBLK, 256, 0, stream>>>(dst, blockHist);
    k_p2a<<<NBUK, 256, 0, stream>>>(blockHist, colScan, bucketTotal);
    k_p2b<<<1,    512, 0, stream>>>(bucketTotal, bucketBase, row_ptr);
    k_p3 <<<NBLK, 256, 0, stream>>>(src, dst, colScan, bucketBase, ebuf);
    k_p4 <<<NBUK, 256, 0, stream>>>(ebuf, bucketBase, row_ptr, csr_src, csr_dst, dinv, selfw);
    k_w  <<<(N_EDGES + 255) / 256, 256, 0, stream>>>(csr_src, csr_dst, dinv, csr_w, batch, cnt);

    const float* curIn = x;
    for (int l = 0; l < 3; l++){
        k_gemm<<<(N_NODES + 63) / 64, 256, 0, stream>>>(
            curIn, wpack + l * 8192,
            l ? ssh + (l - 1) * 256       : nullptr,
            l ? ssh + (l - 1) * 256 + 128 : nullptr,
            tbuf, l ? 1 : 0);
        k_agg<<<25000, 256, 0, stream>>>(
            tbuf, row_ptr, csr_src, csr_w, selfw,
            bs + l * 128, hbuf);
        k_stats<<<500, 256, 0, stream>>>(
            hbuf, stats + l * 256, stats + l * 256 + 128,
            gammas + l * 128, betas + l * 128,
            ssh + l * 256, ssh + l * 256 + 128, done + l);
        curIn = hbuf;
    }

    k_pool<<<391, 256, 0, stream>>>(hbuf, batch, ssh + 2 * 256, ssh + 2 * 256 + 128, pool);
    k_head<<<512, 128, 0, stream>>>(pool, cnt, W1, b1, W2, b2, out);
}

// Round 13
// 509.810 us; speedup vs baseline: 1.3880x; 1.0368x over previous
//
#include <hip/hip_runtime.h>
#include <hip/hip_bf16.h>
#include <hip/hip_fp16.h>

#define N_NODES 100000
#define N_EDGES 800000
#define N_GRAPHS 512
#define D 128
#define EPSV 1e-5f

// radix-bucket CSR build params (256-node buckets)
#define NBLK 256
#define EPB  3125
#define NBUK 391          // ceil(100000/256)
#define MAXB 3072

// MFMA GEMM LDS layout (dwords): Ah 64 rows x 68dw, Wt2 128 cols x 68dw
#define LSTR 68
#define WOFF 4352

typedef _Float16 half8 __attribute__((ext_vector_type(8)));
typedef float floatx16 __attribute__((ext_vector_type(16)));

__device__ __forceinline__ float relu_f(float x){ return fmaxf(x, 0.0f); }

// ---------------- FRONT: p1 histogram (blocks 0..255) | wprep+zero+cnt (256..351)
__global__ __launch_bounds__(256) void k_front(const int* __restrict__ dst,
                                               int* __restrict__ blockHist,
                                               const float* __restrict__ Ws,
                                               unsigned int* __restrict__ wpack,
                                               unsigned int* __restrict__ zbase,
                                               int zn,
                                               const int* __restrict__ batch,
                                               float* __restrict__ cnt)
{
    __shared__ int h[NBUK];
    int j = blockIdx.x, t = threadIdx.x;
    if (j < NBLK){
        for (int u = t; u < NBUK; u += 256) h[u] = 0;
        __syncthreads();
        int e0 = j * EPB;
        for (int e = e0 + t; e < e0 + EPB; e += 256)
            atomicAdd(&h[dst[e] >> 8], 1);
        __syncthreads();
        for (int u = t; u < NBUK; u += 256) blockHist[j * NBUK + u] = h[u];
    } else {
        int b = j - NBLK;                 // 0..95
        int idx = b * 256 + t;
        if (idx < 3 * 128 * 64){
            int l  = idx >> 13;
            int r  = idx & 8191;
            int c  = r >> 6;
            int k2 = r & 63;
            const float* W = Ws + l * D * D;
            __half2 hh = __floats2half2_rn(W[(size_t)(2 * k2) * D + c],
                                           W[(size_t)(2 * k2 + 1) * D + c]);
            wpack[idx] = *(unsigned int*)&hh;
        }
        int stride = 96 * 256;
        for (int i = idx; i < zn; i += stride) zbase[i] = 0u;
        if (idx < N_GRAPHS){
            int g = idx;
            int lo = 0, hi = N_NODES;
            while (lo < hi){ int m = (lo + hi) >> 1; if (batch[m] < g) lo = m + 1; else hi = m; }
            int lb = lo;
            lo = 0; hi = N_NODES;
            while (lo < hi){ int m = (lo + hi) >> 1; if (batch[m] < g + 1) lo = m + 1; else hi = m; }
            cnt[g] = (float)(lo - lb);
        }
    }
}

// ---------------- P2a: per-bucket column scan (NBUK blocks, parallel) ----------
__global__ __launch_bounds__(256) void k_p2a(const int* __restrict__ blockHist,
                                             int* __restrict__ colScan,
                                             int* __restrict__ bucketTotal)
{
    __shared__ int sd[256];
    int b = blockIdx.x, t = threadIdx.x;
    int v = blockHist[t * NBUK + b];
    sd[t] = v;
    __syncthreads();
    for (int off = 1; off < 256; off <<= 1){
        int u = (t >= off) ? sd[t - off] : 0;
        __syncthreads();
        sd[t] += u;
        __syncthreads();
    }
    colScan[t * NBUK + b] = sd[t] - v;
    if (t == 255) bucketTotal[b] = sd[255];
}

// ---------------- P2b: bucket-base scan (1 block x 512 thr) ----------------
__global__ __launch_bounds__(512) void k_p2b(const int* __restrict__ bucketTotal,
                                             int* __restrict__ bucketBase,
                                             int* __restrict__ row_ptr)
{
    __shared__ int sd[512];
    int b = threadIdx.x;
    int v = (b < NBUK) ? bucketTotal[b] : 0;
    sd[b] = v;
    __syncthreads();
    for (int off = 1; off < 512; off <<= 1){
        int u = (b >= off) ? sd[b - off] : 0;
        __syncthreads();
        sd[b] += u;
        __syncthreads();
    }
    if (b < NBUK) bucketBase[b] = sd[b] - v;
    if (b == 0){
        bucketBase[NBUK] = N_EDGES;
        row_ptr[N_NODES] = N_EDGES;
    }
}

// ---------------- P3: scatter edges into bucket-sorted ebuf (LDS cursors) ------
__global__ __launch_bounds__(256) void k_p3(const int* __restrict__ src,
                                            const int* __restrict__ dst,
                                            const int* __restrict__ colScan,
                                            const int* __restrict__ bucketBase,
                                            int2* __restrict__ ebuf)
{
    __shared__ int cur[NBUK];
    int j = blockIdx.x, t = threadIdx.x;
    for (int u = t; u < NBUK; u += 256)
        cur[u] = bucketBase[u] + colScan[j * NBUK + u];
    __syncthreads();
    int e0 = j * EPB;
    for (int e = e0 + t; e < e0 + EPB; e += 256){
        int s = src[e], d = dst[e];
        int pos = atomicAdd(&cur[d >> 8], 1);
        int2 v; v.x = s; v.y = d;
        ebuf[pos] = v;
    }
}

// ---------------- P4: per-bucket counting sort -> row_ptr, CSR, dinv, selfw ----
__global__ __launch_bounds__(256) void k_p4(const int2* __restrict__ ebuf,
                                            const int* __restrict__ bucketBase,
                                            int* __restrict__ row_ptr,
                                            int* __restrict__ csr_src,
                                            int* __restrict__ csr_dst,
                                            float* __restrict__ dinv,
                                            float* __restrict__ selfw)
{
    __shared__ int2 stash[MAXB];
    __shared__ int bins[256];
    __shared__ int sd[256];
    int b = blockIdx.x, t = threadIdx.x;
    int base = bucketBase[b];
    int cntb = bucketBase[b + 1] - base;
    bool st = (cntb <= MAXB);
    bins[t] = 0;
    __syncthreads();
    for (int i = t; i < cntb; i += 256){
        int2 ed = ebuf[base + i];
        if (st) stash[i] = ed;
        atomicAdd(&bins[ed.y & 255], 1);
    }
    __syncthreads();
    int a0 = bins[t];
    sd[t] = a0;
    __syncthreads();
    for (int off = 1; off < 256; off <<= 1){
        int v = (t >= off) ? sd[t - off] : 0;
        __syncthreads();
        sd[t] += v;
        __syncthreads();
    }
    int pex = sd[t] - a0;
    int node = b * 256 + t;
    if (node < N_NODES){
        row_ptr[node] = base + pex;
        float d = (float)(a0 + 1);
        dinv[node]  = rsqrtf(d);
        selfw[node] = 1.0f / d;
    }
    __syncthreads();
    bins[t] = pex;
    __syncthreads();
    for (int i = t; i < cntb; i += 256){
        int2 ed = st ? stash[i] : ebuf[base + i];
        int pos = atomicAdd(&bins[ed.y & 255], 1);
        csr_src[base + pos] = ed.x;
        csr_dst[base + pos] = ed.y;
    }
}

// ---------------- edge weights ----------------
__global__ __launch_bounds__(256) void k_w(const int* __restrict__ csr_src,
                                           const int* __restrict__ csr_dst,
                                           const float* __restrict__ dinv,
                                           float* __restrict__ csr_w)
{
    int p = blockIdx.x * 256 + threadIdx.x;
    if (p < N_EDGES)
        csr_w[p] = dinv[csr_src[p]] * dinv[csr_dst[p]];
}

// ---------------- MFMA GEMM v2: A staged via LDS (coalesced), W prepacked ------
__global__ __launch_bounds__(256) void k_gemm(const float* __restrict__ A,
                                              const unsigned int* __restrict__ wp,
                                              const float* __restrict__ scale,
                                              const float* __restrict__ shift,
                                              __half* __restrict__ outh,
                                              int useBn)
{
    __shared__ unsigned int lds32[WOFF + 128 * LSTR];   // 52224 B
    int tid = threadIdx.x;
    int rowBase = blockIdx.x * 64;

    // ---- stage A (64 x 128) fp16, BN+ReLU fused ----
    #pragma unroll
    for (int rep = 0; rep < 8; rep++){
        int f  = rep * 256 + tid;
        int m  = f >> 5;
        int c4 = f & 31;
        int row = rowBase + m;
        if (row >= N_NODES) row = N_NODES - 1;
        float4 v = *(const float4*)(A + (size_t)row * D + c4 * 4);
        if (useBn){
            float4 sc = *(const float4*)(scale + c4 * 4);
            float4 sh = *(const float4*)(shift + c4 * 4);
            v.x = relu_f(fmaf(v.x, sc.x, sh.x));
            v.y = relu_f(fmaf(v.y, sc.y, sh.y));
            v.z = relu_f(fmaf(v.z, sc.z, sh.z));
            v.w = relu_f(fmaf(v.w, sc.w, sh.w));
        }
        __half2 h0 = __floats2half2_rn(v.x, v.y);
        __half2 h1 = __floats2half2_rn(v.z, v.w);
        uint2 u; u.x = *(unsigned int*)&h0; u.y = *(unsigned int*)&h1;
        *(uint2*)&lds32[m * LSTR + 2 * c4] = u;
    }
    // ---- stage prepacked W^T via uint4 copy ----
    {
        const uint4* gw = (const uint4*)wp;
        #pragma unroll
        for (int rep = 0; rep < 8; rep++){
            int f = rep * 256 + tid;
            int c = f >> 4;
            int q = f & 15;
            uint4 v = gw[f];
            *(uint4*)&lds32[WOFF + c * LSTR + 4 * q] = v;
        }
    }
    __syncthreads();

    int lane = tid & 63, wv = tid >> 6;
    int quad = lane >> 5;
    int ml   = (lane & 31) + (wv & 1) * 32;
    int cA   = (wv >> 1) * 64;
    int c0   = cA + (lane & 31);
    int c1   = c0 + 32;
    const unsigned int* aRow  = lds32 + ml * LSTR;
    const unsigned int* bRow0 = lds32 + WOFF + c0 * LSTR;
    const unsigned int* bRow1 = lds32 + WOFF + c1 * LSTR;
    floatx16 acc0 = {};
    floatx16 acc1 = {};
    #pragma unroll
    for (int ch = 0; ch < 8; ch++){
        int o = ch * 8 + quad * 4;
        half8 af = *(const half8*)(aRow  + o);
        half8 b0 = *(const half8*)(bRow0 + o);
        half8 b1 = *(const half8*)(bRow1 + o);
        acc0 = __builtin_amdgcn_mfma_f32_32x32x16_f16(af, b0, acc0, 0, 0, 0);
        acc1 = __builtin_amdgcn_mfma_f32_32x32x16_f16(af, b1, acc1, 0, 0, 0);
    }
    int rBase = rowBase + (wv & 1) * 32 + 4 * quad;
    #pragma unroll
    for (int r = 0; r < 16; r++){
        int outRow = rBase + (r & 3) + 8 * (r >> 2);
        if (outRow < N_NODES){
            outh[(size_t)outRow * D + c0] = __float2half(acc0[r]);
            outh[(size_t)outRow * D + c1] = __float2half(acc1[r]);
        }
    }
}

// ---------------- edge aggregation + bias (fp16 gathers, fp32 accum/out) -------
__global__ __launch_bounds__(256) void k_agg(const __half* __restrict__ t,
                                             const int* __restrict__ row_ptr,
                                             const int* __restrict__ csr_src,
                                             const float* __restrict__ csr_w,
                                             const float* __restrict__ selfw,
                                             const float* __restrict__ bias,
                                             float* __restrict__ outb)
{
    int lane = threadIdx.x & 63;
    int i = (blockIdx.x * blockDim.x + threadIdx.x) >> 6;
    if (i >= N_NODES) return;
    const __half2* t2 = (const __half2*)t;
    int p0 = row_ptr[i], p1 = row_ptr[i + 1];
    float sw = selfw[i];
    float2 a = __half22float2(t2[(size_t)i * 64 + lane]);
    float ax = a.x * sw, ay = a.y * sw;
    int p = p0;
    for (; p + 8 <= p1; p += 8){
        int s[8]; float wv8[8];
        #pragma unroll
        for (int j = 0; j < 8; j++){ s[j] = csr_src[p + j]; }
        #pragma unroll
        for (int j = 0; j < 8; j++){ wv8[j] = csr_w[p + j]; }
        __half2 v[8];
        #pragma unroll
        for (int j = 0; j < 8; j++) v[j] = t2[(size_t)s[j] * 64 + lane];
        #pragma unroll
        for (int j = 0; j < 8; j++){
            float2 f = __half22float2(v[j]);
            ax = fmaf(wv8[j], f.x, ax);
            ay = fmaf(wv8[j], f.y, ay);
        }
    }
    for (; p + 4 <= p1; p += 4){
        int   s0 = csr_src[p],   s1 = csr_src[p+1], s2 = csr_src[p+2], s3 = csr_src[p+3];
        float w0 = csr_w[p],     w1 = csr_w[p+1],   w2 = csr_w[p+2],   w3 = csr_w[p+3];
        float2 v0 = __half22float2(t2[(size_t)s0 * 64 + lane]);
        float2 v1 = __half22float2(t2[(size_t)s1 * 64 + lane]);
        float2 v2 = __half22float2(t2[(size_t)s2 * 64 + lane]);
        float2 v3 = __half22float2(t2[(size_t)s3 * 64 + lane]);
        ax = fmaf(w0, v0.x, ax); ay = fmaf(w0, v0.y, ay);
        ax = fmaf(w1, v1.x, ax); ay = fmaf(w1, v1.y, ay);
        ax = fmaf(w2, v2.x, ax); ay = fmaf(w2, v2.y, ay);
        ax = fmaf(w3, v3.x, ax); ay = fmaf(w3, v3.y, ay);
    }
    for (; p < p1; ++p){
        int s = csr_src[p];
        float w = csr_w[p];
        float2 v = __half22float2(t2[(size_t)s * 64 + lane]);
        ax = fmaf(w, v.x, ax);
        ay = fmaf(w, v.y, ay);
    }
    float2 b2 = ((const float2*)bias)[lane];
    float2 o; o.x = ax + b2.x; o.y = ay + b2.y;
    ((float2*)outb)[(size_t)i * 64 + lane] = o;
}

// ---------------- BN stats (fp32 h) + fused finalize ----------------
__global__ __launch_bounds__(256) void k_stats(const float* __restrict__ h,
                                               float* __restrict__ S,
                                               float* __restrict__ Q,
                                               const float* __restrict__ gamma,
                                               const float* __restrict__ beta,
                                               float* __restrict__ sc,
                                               float* __restrict__ sh,
                                               int* __restrict__ done)
{
    __shared__ float sS[8][128];
    __shared__ float sQ[8][128];
    __shared__ int isLast;
    int g  = threadIdx.x >> 5;
    int c4 = threadIdx.x & 31;
    int r0 = blockIdx.x * 200;
    const float4* h4 = (const float4*)h;
    float4 s = make_float4(0.f, 0.f, 0.f, 0.f);
    float4 q = make_float4(0.f, 0.f, 0.f, 0.f);
    for (int r = r0 + g; r < r0 + 200; r += 8){
        float4 v = h4[(size_t)r * 32 + c4];
        s.x += v.x; s.y += v.y; s.z += v.z; s.w += v.w;
        q.x = fmaf(v.x, v.x, q.x);
        q.y = fmaf(v.y, v.y, q.y);
        q.z = fmaf(v.z, v.z, q.z);
        q.w = fmaf(v.w, v.w, q.w);
    }
    *(float4*)&sS[g][c4 * 4] = s;
    *(float4*)&sQ[g][c4 * 4] = q;
    __syncthreads();
    int f = threadIdx.x;
    if (f < 128){
        float acc = 0.f;
        #pragma unroll
        for (int j = 0; j < 8; j++) acc += sS[j][f];
        atomicAdd(&S[f], acc);
    } else {
        int f2 = f - 128;
        float acc = 0.f;
        #pragma unroll
        for (int j = 0; j < 8; j++) acc += sQ[j][f2];
        atomicAdd(&Q[f2], acc);
    }
    __threadfence();
    __syncthreads();
    if (threadIdx.x == 0)
        isLast = (atomicAdd(done, 1) == (int)gridDim.x - 1);
    __syncthreads();
    if (isLast && f < 128){
        float Sv = atomicAdd(&S[f], 0.0f);
        float Qv = atomicAdd(&Q[f], 0.0f);
        float mean = Sv * (1.0f / N_NODES);
        float var  = fmaxf(Qv * (1.0f / N_NODES) - mean * mean, 0.0f);
        float inv  = rsqrtf(var + EPSV);
        float gm = gamma[f] * inv;
        sc[f] = gm;
        sh[f] = beta[f] - mean * gm;
    }
}

// ---------------- pooled sum per graph (fp32 h) ----------------
#define CHUNK 64
__global__ __launch_bounds__(256) void k_pool(const float* __restrict__ h,
                                              const int* __restrict__ batch,
                                              const float* __restrict__ sc,
                                              const float* __restrict__ sh,
                                              float* __restrict__ pool)
{
    int lane = threadIdx.x & 63;
    int wave = (blockIdx.x * blockDim.x + threadIdx.x) >> 6;
    int i0 = wave * CHUNK;
    if (i0 >= N_NODES) return;
    int i1 = min(N_NODES, i0 + CHUNK);
    const float2* h2 = (const float2*)h;
    float2 scv = ((const float2*)sc)[lane];
    float2 shv = ((const float2*)sh)[lane];
    int g = batch[i0];
    float ax = 0.f, ay = 0.f;
    for (int i = i0; i < i1; ++i){
        int gi = batch[i];
        if (gi != g){
            atomicAdd(&pool[g * 128 + 2 * lane],     ax);
            atomicAdd(&pool[g * 128 + 2 * lane + 1], ay);
            ax = 0.f; ay = 0.f; g = gi;
        }
        float2 v = h2[(size_t)i * 64 + lane];
        ax += relu_f(fmaf(v.x, scv.x, shv.x));
        ay += relu_f(fmaf(v.y, scv.y, shv.y));
    }
    atomicAdd(&pool[g * 128 + 2 * lane],     ax);
    atomicAdd(&pool[g * 128 + 2 * lane + 1], ay);
}

// ---------------- MLP head ----------------
__global__ __launch_bounds__(128) void k_head(const float* __restrict__ pool,
                                              const float* __restrict__ cnt,
                                              const float* __restrict__ W1,
                                              const float* __restrict__ b1,
                                              const float* __restrict__ W2,
                                              const float* __restrict__ b2,
                                              float* __restrict__ out)
{
    __shared__ float z[128];
    __shared__ float red[128];
    int g = blockIdx.x, f = threadIdx.x;
    float c = fmaxf(cnt[g], 1.0f);
    z[f] = pool[g * 128 + f] / c;
    __syncthreads();
    float a = b1[f];
    #pragma unroll 8
    for (int k = 0; k < 128; k++)
        a = fmaf(z[k], W1[k * 128 + f], a);
    a = relu_f(a);
    red[f] = a * W2[f];
    __syncthreads();
    for (int s2 = 64; s2 > 0; s2 >>= 1){
        if (f < s2) red[f] += red[f + s2];
        __syncthreads();
    }
    if (f == 0) out[g] = red[0] + b2[0];
}

extern "C" void kernel_launch(void* const* d_in, const int* in_sizes, int n_in,
                              void* d_out, int out_size, void* d_ws, size_t ws_size,
                              hipStream_t stream)
{
    const float* x      = (const float*)d_in[0];
    const int*   ei     = (const int*)d_in[1];
    const int*   batch  = (const int*)d_in[2];
    const float* Ws     = (const float*)d_in[3];
    const float* bs     = (const float*)d_in[4];
    const float* gammas = (const float*)d_in[5];
    const float* betas  = (const float*)d_in[6];
    const float* W1     = (const float*)d_in[7];
    const float* b1     = (const float*)d_in[8];
    const float* W2     = (const float*)d_in[9];
    const float* b2     = (const float*)d_in[10];
    float* out = (float*)d_out;

    const int* src = ei;
    const int* dst = ei + N_EDGES;

    char* w = (char*)d_ws;
    size_t off = 0;
    auto alloc = [&](size_t bytes) -> void* {
        void* p = w + off;
        off += (bytes + 255) & ~(size_t)255;
        return p;
    };
    int*   row_ptr     = (int*)  alloc((size_t)(N_NODES + 1) * 4);
    float* dinv        = (float*)alloc((size_t)N_NODES * 4);
    float* selfw       = (float*)alloc((size_t)N_NODES * 4);
    int*   csr_src     = (int*)  alloc((size_t)N_EDGES * 4);
    float* csr_w       = (float*)alloc((size_t)N_EDGES * 4);
    int*   blockHist   = (int*)  alloc((size_t)NBLK * NBUK * 4);
    int*   colScan     = (int*)  alloc((size_t)NBLK * NBUK * 4);
    int*   bucketBase  = (int*)  alloc((size_t)(NBUK + 1) * 4);
    int*   bucketTotal = (int*)  alloc((size_t)NBUK * 4);
    unsigned int* wpack = (unsigned int*)alloc((size_t)3 * 128 * 64 * 4);
    size_t zoff = off;                       // --- zero-span start ---
    float* stats       = (float*)alloc(3 * 256 * 4);   // per layer: S, Q
    int*   done        = (int*)  alloc(3 * 4);
    float* pool        = (float*)alloc((size_t)N_GRAPHS * 128 * 4);
    size_t zend = off;                       // --- zero-span end ---
    float* cnt         = (float*)alloc((size_t)N_GRAPHS * 4);
    float* ssh         = (float*)alloc(3 * 256 * 4);   // per layer: scale, shift
    __half* tbuf       = (__half*)alloc((size_t)N_NODES * 128 * 2);  // fp16 gather table
    float* hbuf        = (float*)alloc((size_t)N_NODES * 128 * 4);   // fp32 h
    if (off > ws_size) return;

    // alias scratch (consumed before tbuf/hbuf are first written; stream-ordered)
    int2* ebuf    = (int2*)tbuf;    // 6.4 MB < 25.6 MB
    int*  csr_dst = (int*)hbuf;     // 3.2 MB < 51.2 MB

    k_front<<<NBLK + 96, 256, 0, stream>>>(dst, blockHist, Ws, wpack,
                                           (unsigned int*)(w + zoff),
                                           (int)((zend - zoff) >> 2),
                                           batch, cnt);
    k_p2a<<<NBUK, 256, 0, stream>>>(blockHist, colScan, bucketTotal);
    k_p2b<<<1,    512, 0, stream>>>(bucketTotal, bucketBase, row_ptr);
    k_p3 <<<NBLK, 256, 0, stream>>>(src, dst, colScan, bucketBase, ebuf);
    k_p4 <<<NBUK, 256, 0, stream>>>(ebuf, bucketBase, row_ptr, csr_src, csr_dst, dinv, selfw);
    k_w  <<<(N_EDGES + 255) / 256, 256, 0, stream>>>(csr_src, csr_dst, dinv, csr_w);

    const float* curIn = x;
    for (int l = 0; l < 3; l++){
        k_gemm<<<(N_NODES + 63) / 64, 256, 0, stream>>>(
            curIn, wpack + l * 8192,
            l ? ssh + (l - 1) * 256       : nullptr,
            l ? ssh + (l - 1) * 256 + 128 : nullptr,
            tbuf, l ? 1 : 0);
        k_agg<<<25000, 256, 0, stream>>>(
            tbuf, row_ptr, csr_src, csr_w, selfw,
            bs + l * 128, hbuf);
        k_stats<<<500, 256, 0, stream>>>(
            hbuf, stats + l * 256, stats + l * 256 + 128,
            gammas + l * 128, betas + l * 128,
            ssh + l * 256, ssh + l * 256 + 128, done + l);
        curIn = hbuf;
    }

    k_pool<<<391, 256, 0, stream>>>(hbuf, batch, ssh + 2 * 256, ssh + 2 * 256 + 128, pool);
    k_head<<<512, 128, 0, stream>>>(pool, cnt, W1, b1, W2, b2, out);
}

// Round 14
// 429.098 us; speedup vs baseline: 1.6490x; 1.1881x over previous
//
#include <hip/hip_runtime.h>
#include <hip/hip_bf16.h>
#include <hip/hip_fp16.h>

#define N_NODES 100000
#define N_EDGES 800000
#define N_GRAPHS 512
#define D 128
#define EPSV 1e-5f

// radix-bucket CSR build params (256-node buckets)
#define NBLK 256
#define EPB  3125
#define NBUK 391          // ceil(100000/256)
#define MAXB 3072

// MFMA GEMM LDS layout (dwords): Ah 64 rows x 68dw, Wt2 128 cols x 68dw
#define LSTR 68
#define WOFF 4352

#define NSLOT 256         // stats scatter slots (queue depth 25000/256 ~ 98)

typedef _Float16 half8 __attribute__((ext_vector_type(8)));
typedef float floatx16 __attribute__((ext_vector_type(16)));

__device__ __forceinline__ float relu_f(float x){ return fmaxf(x, 0.0f); }

// ---------------- FRONT: p1 histogram (blocks 0..255) | wprep+zero+cnt (256..351)
__global__ __launch_bounds__(256) void k_front(const int* __restrict__ dst,
                                               int* __restrict__ blockHist,
                                               const float* __restrict__ Ws,
                                               unsigned int* __restrict__ wpack,
                                               unsigned int* __restrict__ zbase,
                                               int zn,
                                               const int* __restrict__ batch,
                                               float* __restrict__ cnt)
{
    __shared__ int h[NBUK];
    int j = blockIdx.x, t = threadIdx.x;
    if (j < NBLK){
        for (int u = t; u < NBUK; u += 256) h[u] = 0;
        __syncthreads();
        int e0 = j * EPB;
        for (int e = e0 + t; e < e0 + EPB; e += 256)
            atomicAdd(&h[dst[e] >> 8], 1);
        __syncthreads();
        for (int u = t; u < NBUK; u += 256) blockHist[j * NBUK + u] = h[u];
    } else {
        int b = j - NBLK;                 // 0..95
        int idx = b * 256 + t;
        if (idx < 3 * 128 * 64){
            int l  = idx >> 13;
            int r  = idx & 8191;
            int c  = r >> 6;
            int k2 = r & 63;
            const float* W = Ws + l * D * D;
            __half2 hh = __floats2half2_rn(W[(size_t)(2 * k2) * D + c],
                                           W[(size_t)(2 * k2 + 1) * D + c]);
            wpack[idx] = *(unsigned int*)&hh;
        }
        int stride = 96 * 256;
        for (int i = idx; i < zn; i += stride) zbase[i] = 0u;
        if (idx < N_GRAPHS){
            int g = idx;
            int lo = 0, hi = N_NODES;
            while (lo < hi){ int m = (lo + hi) >> 1; if (batch[m] < g) lo = m + 1; else hi = m; }
            int lb = lo;
            lo = 0; hi = N_NODES;
            while (lo < hi){ int m = (lo + hi) >> 1; if (batch[m] < g + 1) lo = m + 1; else hi = m; }
            cnt[g] = (float)(lo - lb);
        }
    }
}

// ---------------- P2a: per-bucket column scan (NBUK blocks, parallel) ----------
__global__ __launch_bounds__(256) void k_p2a(const int* __restrict__ blockHist,
                                             int* __restrict__ colScan,
                                             int* __restrict__ bucketTotal)
{
    __shared__ int sd[256];
    int b = blockIdx.x, t = threadIdx.x;
    int v = blockHist[t * NBUK + b];
    sd[t] = v;
    __syncthreads();
    for (int off = 1; off < 256; off <<= 1){
        int u = (t >= off) ? sd[t - off] : 0;
        __syncthreads();
        sd[t] += u;
        __syncthreads();
    }
    colScan[t * NBUK + b] = sd[t] - v;
    if (t == 255) bucketTotal[b] = sd[255];
}

// ---------------- P2b: bucket-base scan (1 block x 512 thr) ----------------
__global__ __launch_bounds__(512) void k_p2b(const int* __restrict__ bucketTotal,
                                             int* __restrict__ bucketBase,
                                             int* __restrict__ row_ptr)
{
    __shared__ int sd[512];
    int b = threadIdx.x;
    int v = (b < NBUK) ? bucketTotal[b] : 0;
    sd[b] = v;
    __syncthreads();
    for (int off = 1; off < 512; off <<= 1){
        int u = (b >= off) ? sd[b - off] : 0;
        __syncthreads();
        sd[b] += u;
        __syncthreads();
    }
    if (b < NBUK) bucketBase[b] = sd[b] - v;
    if (b == 0){
        bucketBase[NBUK] = N_EDGES;
        row_ptr[N_NODES] = N_EDGES;
    }
}

// ---------------- P3: scatter edges into bucket-sorted ebuf (LDS cursors) ------
__global__ __launch_bounds__(256) void k_p3(const int* __restrict__ src,
                                            const int* __restrict__ dst,
                                            const int* __restrict__ colScan,
                                            const int* __restrict__ bucketBase,
                                            int2* __restrict__ ebuf)
{
    __shared__ int cur[NBUK];
    int j = blockIdx.x, t = threadIdx.x;
    for (int u = t; u < NBUK; u += 256)
        cur[u] = bucketBase[u] + colScan[j * NBUK + u];
    __syncthreads();
    int e0 = j * EPB;
    for (int e = e0 + t; e < e0 + EPB; e += 256){
        int s = src[e], d = dst[e];
        int pos = atomicAdd(&cur[d >> 8], 1);
        int2 v; v.x = s; v.y = d;
        ebuf[pos] = v;
    }
}

// ---------------- P4: per-bucket counting sort -> row_ptr, CSR, dinv, selfw ----
__global__ __launch_bounds__(256) void k_p4(const int2* __restrict__ ebuf,
                                            const int* __restrict__ bucketBase,
                                            int* __restrict__ row_ptr,
                                            int* __restrict__ csr_src,
                                            int* __restrict__ csr_dst,
                                            float* __restrict__ dinv,
                                            float* __restrict__ selfw)
{
    __shared__ int2 stash[MAXB];
    __shared__ int bins[256];
    __shared__ int sd[256];
    int b = blockIdx.x, t = threadIdx.x;
    int base = bucketBase[b];
    int cntb = bucketBase[b + 1] - base;
    bool st = (cntb <= MAXB);
    bins[t] = 0;
    __syncthreads();
    for (int i = t; i < cntb; i += 256){
        int2 ed = ebuf[base + i];
        if (st) stash[i] = ed;
        atomicAdd(&bins[ed.y & 255], 1);
    }
    __syncthreads();
    int a0 = bins[t];
    sd[t] = a0;
    __syncthreads();
    for (int off = 1; off < 256; off <<= 1){
        int v = (t >= off) ? sd[t - off] : 0;
        __syncthreads();
        sd[t] += v;
        __syncthreads();
    }
    int pex = sd[t] - a0;
    int node = b * 256 + t;
    if (node < N_NODES){
        row_ptr[node] = base + pex;
        float d = (float)(a0 + 1);
        dinv[node]  = rsqrtf(d);
        selfw[node] = 1.0f / d;
    }
    __syncthreads();
    bins[t] = pex;
    __syncthreads();
    for (int i = t; i < cntb; i += 256){
        int2 ed = st ? stash[i] : ebuf[base + i];
        int pos = atomicAdd(&bins[ed.y & 255], 1);
        csr_src[base + pos] = ed.x;
        csr_dst[base + pos] = ed.y;
    }
}

// ---------------- edge weights ----------------
__global__ __launch_bounds__(256) void k_w(const int* __restrict__ csr_src,
                                           const int* __restrict__ csr_dst,
                                           const float* __restrict__ dinv,
                                           float* __restrict__ csr_w)
{
    int p = blockIdx.x * 256 + threadIdx.x;
    if (p < N_EDGES)
        csr_w[p] = dinv[csr_src[p]] * dinv[csr_dst[p]];
}

// ---------------- MFMA GEMM v2: A staged via LDS (coalesced), W prepacked ------
__global__ __launch_bounds__(256) void k_gemm(const float* __restrict__ A,
                                              const unsigned int* __restrict__ wp,
                                              const float* __restrict__ scale,
                                              const float* __restrict__ shift,
                                              __half* __restrict__ outh,
                                              int useBn)
{
    __shared__ unsigned int lds32[WOFF + 128 * LSTR];   // 52224 B
    int tid = threadIdx.x;
    int rowBase = blockIdx.x * 64;

    #pragma unroll
    for (int rep = 0; rep < 8; rep++){
        int f  = rep * 256 + tid;
        int m  = f >> 5;
        int c4 = f & 31;
        int row = rowBase + m;
        if (row >= N_NODES) row = N_NODES - 1;
        float4 v = *(const float4*)(A + (size_t)row * D + c4 * 4);
        if (useBn){
            float4 sc = *(const float4*)(scale + c4 * 4);
            float4 sh = *(const float4*)(shift + c4 * 4);
            v.x = relu_f(fmaf(v.x, sc.x, sh.x));
            v.y = relu_f(fmaf(v.y, sc.y, sh.y));
            v.z = relu_f(fmaf(v.z, sc.z, sh.z));
            v.w = relu_f(fmaf(v.w, sc.w, sh.w));
        }
        __half2 h0 = __floats2half2_rn(v.x, v.y);
        __half2 h1 = __floats2half2_rn(v.z, v.w);
        uint2 u; u.x = *(unsigned int*)&h0; u.y = *(unsigned int*)&h1;
        *(uint2*)&lds32[m * LSTR + 2 * c4] = u;
    }
    {
        const uint4* gw = (const uint4*)wp;
        #pragma unroll
        for (int rep = 0; rep < 8; rep++){
            int f = rep * 256 + tid;
            int c = f >> 4;
            int q = f & 15;
            uint4 v = gw[f];
            *(uint4*)&lds32[WOFF + c * LSTR + 4 * q] = v;
        }
    }
    __syncthreads();

    int lane = tid & 63, wv = tid >> 6;
    int quad = lane >> 5;
    int ml   = (lane & 31) + (wv & 1) * 32;
    int cA   = (wv >> 1) * 64;
    int c0   = cA + (lane & 31);
    int c1   = c0 + 32;
    const unsigned int* aRow  = lds32 + ml * LSTR;
    const unsigned int* bRow0 = lds32 + WOFF + c0 * LSTR;
    const unsigned int* bRow1 = lds32 + WOFF + c1 * LSTR;
    floatx16 acc0 = {};
    floatx16 acc1 = {};
    #pragma unroll
    for (int ch = 0; ch < 8; ch++){
        int o = ch * 8 + quad * 4;
        half8 af = *(const half8*)(aRow  + o);
        half8 b0 = *(const half8*)(bRow0 + o);
        half8 b1 = *(const half8*)(bRow1 + o);
        acc0 = __builtin_amdgcn_mfma_f32_32x32x16_f16(af, b0, acc0, 0, 0, 0);
        acc1 = __builtin_amdgcn_mfma_f32_32x32x16_f16(af, b1, acc1, 0, 0, 0);
    }
    int rBase = rowBase + (wv & 1) * 32 + 4 * quad;
    #pragma unroll
    for (int r = 0; r < 16; r++){
        int outRow = rBase + (r & 3) + 8 * (r >> 2);
        if (outRow < N_NODES){
            outh[(size_t)outRow * D + c0] = __float2half(acc0[r]);
            outh[(size_t)outRow * D + c1] = __float2half(acc1[r]);
        }
    }
}

// ---------------- edge aggregation + bias + slot-scattered BN stats ------------
// Per-block LDS reduce (R5 pattern) but atomics scattered across NSLOT slots:
// queue depth per address ~98 (25000/256) -- fixes R5's same-address pileup.
__global__ __launch_bounds__(256) void k_agg(const __half* __restrict__ t,
                                             const int* __restrict__ row_ptr,
                                             const int* __restrict__ csr_src,
                                             const float* __restrict__ csr_w,
                                             const float* __restrict__ selfw,
                                             const float* __restrict__ bias,
                                             float* __restrict__ outb,
                                             float* __restrict__ Spart,
                                             float* __restrict__ Qpart)
{
    __shared__ float ldsS[4][128];
    __shared__ float ldsQ[4][128];
    int lane = threadIdx.x & 63;
    int wv   = threadIdx.x >> 6;
    int i = blockIdx.x * 4 + wv;           // grid covers exactly N_NODES waves
    const __half2* t2 = (const __half2*)t;
    int p0 = row_ptr[i], p1 = row_ptr[i + 1];
    float sw = selfw[i];
    float2 a = __half22float2(t2[(size_t)i * 64 + lane]);
    float ax = a.x * sw, ay = a.y * sw;
    int p = p0;
    for (; p + 8 <= p1; p += 8){
        int s[8]; float wv8[8];
        #pragma unroll
        for (int j = 0; j < 8; j++){ s[j] = csr_src[p + j]; }
        #pragma unroll
        for (int j = 0; j < 8; j++){ wv8[j] = csr_w[p + j]; }
        __half2 v[8];
        #pragma unroll
        for (int j = 0; j < 8; j++) v[j] = t2[(size_t)s[j] * 64 + lane];
        #pragma unroll
        for (int j = 0; j < 8; j++){
            float2 f = __half22float2(v[j]);
            ax = fmaf(wv8[j], f.x, ax);
            ay = fmaf(wv8[j], f.y, ay);
        }
    }
    for (; p + 4 <= p1; p += 4){
        int   s0 = csr_src[p],   s1 = csr_src[p+1], s2 = csr_src[p+2], s3 = csr_src[p+3];
        float w0 = csr_w[p],     w1 = csr_w[p+1],   w2 = csr_w[p+2],   w3 = csr_w[p+3];
        float2 v0 = __half22float2(t2[(size_t)s0 * 64 + lane]);
        float2 v1 = __half22float2(t2[(size_t)s1 * 64 + lane]);
        float2 v2 = __half22float2(t2[(size_t)s2 * 64 + lane]);
        float2 v3 = __half22float2(t2[(size_t)s3 * 64 + lane]);
        ax = fmaf(w0, v0.x, ax); ay = fmaf(w0, v0.y, ay);
        ax = fmaf(w1, v1.x, ax); ay = fmaf(w1, v1.y, ay);
        ax = fmaf(w2, v2.x, ax); ay = fmaf(w2, v2.y, ay);
        ax = fmaf(w3, v3.x, ax); ay = fmaf(w3, v3.y, ay);
    }
    for (; p < p1; ++p){
        int s = csr_src[p];
        float w = csr_w[p];
        float2 v = __half22float2(t2[(size_t)s * 64 + lane]);
        ax = fmaf(w, v.x, ax);
        ay = fmaf(w, v.y, ay);
    }
    float2 b2 = ((const float2*)bias)[lane];
    ax += b2.x; ay += b2.y;
    float2 o; o.x = ax; o.y = ay;
    ((float2*)outb)[(size_t)i * 64 + lane] = o;
    // stats epilogue: per-block reduce, slot-scattered atomics
    ldsS[wv][2 * lane] = ax;       ldsS[wv][2 * lane + 1] = ay;
    ldsQ[wv][2 * lane] = ax * ax;  ldsQ[wv][2 * lane + 1] = ay * ay;
    __syncthreads();
    int tid = threadIdx.x;
    int slotBase = (blockIdx.x & (NSLOT - 1)) * 128;
    if (tid < 128){
        float s = ldsS[0][tid] + ldsS[1][tid] + ldsS[2][tid] + ldsS[3][tid];
        atomicAdd(&Spart[slotBase + tid], s);
    } else {
        int f = tid - 128;
        float q = ldsQ[0][f] + ldsQ[1][f] + ldsQ[2][f] + ldsQ[3][f];
        atomicAdd(&Qpart[slotBase + f], q);
    }
}

// ---------------- finalize: reduce NSLOT slots -> scale/shift (1 block) --------
__global__ __launch_bounds__(256) void k_fin2(const float* __restrict__ Spart,
                                              const float* __restrict__ Qpart,
                                              const float* __restrict__ gamma,
                                              const float* __restrict__ beta,
                                              float* __restrict__ sc,
                                              float* __restrict__ sh)
{
    int t = threadIdx.x;
    int f = t & 127;
    const float* src = (t < 128) ? Spart : Qpart;
    float acc = 0.f;
    for (int s2 = 0; s2 < NSLOT; s2++)
        acc += src[s2 * 128 + f];
    __shared__ float red[256];
    red[t] = acc;
    __syncthreads();
    if (t < 128){
        float Sv = red[t];
        float Qv = red[t + 128];
        float mean = Sv * (1.0f / N_NODES);
        float var  = fmaxf(Qv * (1.0f / N_NODES) - mean * mean, 0.0f);
        float inv  = rsqrtf(var + EPSV);
        float gm = gamma[f] * inv;
        sc[f] = gm;
        sh[f] = beta[f] - mean * gm;
    }
}

// ---------------- pooled sum per graph (fp32 h) ----------------
#define CHUNK 64
__global__ __launch_bounds__(256) void k_pool(const float* __restrict__ h,
                                              const int* __restrict__ batch,
                                              const float* __restrict__ sc,
                                              const float* __restrict__ sh,
                                              float* __restrict__ pool)
{
    int lane = threadIdx.x & 63;
    int wave = (blockIdx.x * blockDim.x + threadIdx.x) >> 6;
    int i0 = wave * CHUNK;
    if (i0 >= N_NODES) return;
    int i1 = min(N_NODES, i0 + CHUNK);
    const float2* h2 = (const float2*)h;
    float2 scv = ((const float2*)sc)[lane];
    float2 shv = ((const float2*)sh)[lane];
    int g = batch[i0];
    float ax = 0.f, ay = 0.f;
    for (int i = i0; i < i1; ++i){
        int gi = batch[i];
        if (gi != g){
            atomicAdd(&pool[g * 128 + 2 * lane],     ax);
            atomicAdd(&pool[g * 128 + 2 * lane + 1], ay);
            ax = 0.f; ay = 0.f; g = gi;
        }
        float2 v = h2[(size_t)i * 64 + lane];
        ax += relu_f(fmaf(v.x, scv.x, shv.x));
        ay += relu_f(fmaf(v.y, scv.y, shv.y));
    }
    atomicAdd(&pool[g * 128 + 2 * lane],     ax);
    atomicAdd(&pool[g * 128 + 2 * lane + 1], ay);
}

// ---------------- MLP head ----------------
__global__ __launch_bounds__(128) void k_head(const float* __restrict__ pool,
                                              const float* __restrict__ cnt,
                                              const float* __restrict__ W1,
                                              const float* __restrict__ b1,
                                              const float* __restrict__ W2,
                                              const float* __restrict__ b2,
                                              float* __restrict__ out)
{
    __shared__ float z[128];
    __shared__ float red[128];
    int g = blockIdx.x, f = threadIdx.x;
    float c = fmaxf(cnt[g], 1.0f);
    z[f] = pool[g * 128 + f] / c;
    __syncthreads();
    float a = b1[f];
    #pragma unroll 8
    for (int k = 0; k < 128; k++)
        a = fmaf(z[k], W1[k * 128 + f], a);
    a = relu_f(a);
    red[f] = a * W2[f];
    __syncthreads();
    for (int s2 = 64; s2 > 0; s2 >>= 1){
        if (f < s2) red[f] += red[f + s2];
        __syncthreads();
    }
    if (f == 0) out[g] = red[0] + b2[0];
}

extern "C" void kernel_launch(void* const* d_in, const int* in_sizes, int n_in,
                              void* d_out, int out_size, void* d_ws, size_t ws_size,
                              hipStream_t stream)
{
    const float* x      = (const float*)d_in[0];
    const int*   ei     = (const int*)d_in[1];
    const int*   batch  = (const int*)d_in[2];
    const float* Ws     = (const float*)d_in[3];
    const float* bs     = (const float*)d_in[4];
    const float* gammas = (const float*)d_in[5];
    const float* betas  = (const float*)d_in[6];
    const float* W1     = (const float*)d_in[7];
    const float* b1     = (const float*)d_in[8];
    const float* W2     = (const float*)d_in[9];
    const float* b2     = (const float*)d_in[10];
    float* out = (float*)d_out;

    const int* src = ei;
    const int* dst = ei + N_EDGES;

    char* w = (char*)d_ws;
    size_t off = 0;
    auto alloc = [&](size_t bytes) -> void* {
        void* p = w + off;
        off += (bytes + 255) & ~(size_t)255;
        return p;
    };
    int*   row_ptr     = (int*)  alloc((size_t)(N_NODES + 1) * 4);
    float* dinv        = (float*)alloc((size_t)N_NODES * 4);
    float* selfw       = (float*)alloc((size_t)N_NODES * 4);
    int*   csr_src     = (int*)  alloc((size_t)N_EDGES * 4);
    float* csr_w       = (float*)alloc((size_t)N_EDGES * 4);
    int*   blockHist   = (int*)  alloc((size_t)NBLK * NBUK * 4);
    int*   colScan     = (int*)  alloc((size_t)NBLK * NBUK * 4);
    int*   bucketBase  = (int*)  alloc((size_t)(NBUK + 1) * 4);
    int*   bucketTotal = (int*)  alloc((size_t)NBUK * 4);
    unsigned int* wpack = (unsigned int*)alloc((size_t)3 * 128 * 64 * 4);
    size_t zoff = off;                       // --- zero-span start ---
    float* stats       = (float*)alloc((size_t)3 * 2 * NSLOT * 128 * 4); // per layer: Spart, Qpart
    float* pool        = (float*)alloc((size_t)N_GRAPHS * 128 * 4);
    size_t zend = off;                       // --- zero-span end ---
    float* cnt         = (float*)alloc((size_t)N_GRAPHS * 4);
    float* ssh         = (float*)alloc(3 * 256 * 4);   // per layer: scale, shift
    __half* tbuf       = (__half*)alloc((size_t)N_NODES * 128 * 2);  // fp16 gather table
    float* hbuf        = (float*)alloc((size_t)N_NODES * 128 * 4);   // fp32 h
    if (off > ws_size) return;

    // alias scratch (consumed before tbuf/hbuf are first written; stream-ordered)
    int2* ebuf    = (int2*)tbuf;    // 6.4 MB < 25.6 MB
    int*  csr_dst = (int*)hbuf;     // 3.2 MB < 51.2 MB

    k_front<<<NBLK + 96, 256, 0, stream>>>(dst, blockHist, Ws, wpack,
                                           (unsigned int*)(w + zoff),
                                           (int)((zend - zoff) >> 2),
                                           batch, cnt);
    k_p2a<<<NBUK, 256, 0, stream>>>(blockHist, colScan, bucketTotal);
    k_p2b<<<1,    512, 0, stream>>>(bucketTotal, bucketBase, row_ptr);
    k_p3 <<<NBLK, 256, 0, stream>>>(src, dst, colScan, bucketBase, ebuf);
    k_p4 <<<NBUK, 256, 0, stream>>>(ebuf, bucketBase, row_ptr, csr_src, csr_dst, dinv, selfw);
    k_w  <<<(N_EDGES + 255) / 256, 256, 0, stream>>>(csr_src, csr_dst, dinv, csr_w);

    const float* curIn = x;
    for (int l = 0; l < 3; l++){
        float* Sp = stats + (size_t)l * 2 * NSLOT * 128;
        float* Qp = Sp + NSLOT * 128;
        k_gemm<<<(N_NODES + 63) / 64, 256, 0, stream>>>(
            curIn, wpack + l * 8192,
            l ? ssh + (l - 1) * 256       : nullptr,
            l ? ssh + (l - 1) * 256 + 128 : nullptr,
            tbuf, l ? 1 : 0);
        k_agg<<<25000, 256, 0, stream>>>(
            tbuf, row_ptr, csr_src, csr_w, selfw,
            bs + l * 128, hbuf, Sp, Qp);
        k_fin2<<<1, 256, 0, stream>>>(
            Sp, Qp, gammas + l * 128, betas + l * 128,
            ssh + l * 256, ssh + l * 256 + 128);
        curIn = hbuf;
    }

    k_pool<<<391, 256, 0, stream>>>(hbuf, batch, ssh + 2 * 256, ssh + 2 * 256 + 128, pool);
    k_head<<<512, 128, 0, stream>>>(pool, cnt, W1, b1, W2, b2, out);
}